// Round 3
// baseline (765.202 us; speedup 1.0000x reference)
//
#include <hip/hip_runtime.h>

#define TOKENS 4096
#define IN_F   8192
#define OUT_F  8192

typedef int v4i __attribute__((ext_vector_type(4)));

__device__ __forceinline__ void gload_lds16(const void* g, void* l) {
    __builtin_amdgcn_global_load_lds(
        (const __attribute__((address_space(1))) void*)g,
        (__attribute__((address_space(3))) void*)l, 16, 0, 0);
}

// ---------------- Kernel 1: per-row absmax + int8 quantize ----------------
__global__ __launch_bounds__(256) void quant_kernel(const float* __restrict__ x,
                                                    signed char* __restrict__ xq,
                                                    float* __restrict__ recip_s) {
    const int row = blockIdx.x;
    const int t   = threadIdx.x;
    const float4* xr = (const float4*)(x + (size_t)row * IN_F);
    float4 v[8];
    float m = 0.f;
#pragma unroll
    for (int i = 0; i < 8; ++i) {
        v[i] = xr[t + 256 * i];
        m = fmaxf(m, fmaxf(fmaxf(fabsf(v[i].x), fabsf(v[i].y)),
                           fmaxf(fabsf(v[i].z), fabsf(v[i].w))));
    }
#pragma unroll
    for (int off = 32; off > 0; off >>= 1)
        m = fmaxf(m, __shfl_xor(m, off));
    __shared__ float wmax[4];
    if ((t & 63) == 0) wmax[t >> 6] = m;
    __syncthreads();
    m = fmaxf(fmaxf(wmax[0], wmax[1]), fmaxf(wmax[2], wmax[3]));
    m = fmaxf(m, 1e-5f);
    const float s = 127.0f / m;          // matches ref: s = 127/clip(max,1e-5)
    if (t == 0) recip_s[row] = m / 127.0f;
    unsigned int* out = (unsigned int*)(xq + (size_t)row * IN_F);
#pragma unroll
    for (int i = 0; i < 8; ++i) {
        int a = (int)fminf(fmaxf(rintf(v[i].x * s), -128.f), 127.f);
        int b = (int)fminf(fmaxf(rintf(v[i].y * s), -128.f), 127.f);
        int c = (int)fminf(fmaxf(rintf(v[i].z * s), -128.f), 127.f);
        int d = (int)fminf(fmaxf(rintf(v[i].w * s), -128.f), 127.f);
        out[t + 256 * i] = (a & 255) | ((b & 255) << 8) | ((c & 255) << 16) | ((d & 255) << 24);
    }
}

// ---------------- Kernel 2: weight int32 {0,1} -> int8 ----------------
__global__ __launch_bounds__(256) void pack_w(const int* __restrict__ w,
                                              unsigned int* __restrict__ w8) {
    const size_t idx = (size_t)blockIdx.x * 256 + threadIdx.x;
    int4 a = ((const int4*)w)[idx];
    w8[idx] = (a.x & 255) | ((a.y & 255) << 8) | ((a.z & 255) << 16) | ((a.w & 255) << 24);
}

// ---------------- Kernel 3: i8 GEMM, 128x256 tile, BK=64 ------------------
// Double-buffered LDS, ONE barrier per K-iter: loads for tile k+1 issued
// right after the barrier into the other buffer, compute on tile k follows.
// LDS chunk swizzle: 16B chunk c of row r stored at position c ^ ((r>>1)&3).
__global__ __launch_bounds__(256, 2) void gemm_kernel(const signed char* __restrict__ A,
                                                      const signed char* __restrict__ B,
                                                      const float* __restrict__ recip_s,
                                                      const float* __restrict__ wscale,
                                                      const float* __restrict__ bias,
                                                      float* __restrict__ out) {
    __shared__ signed char As[2 * 128 * 64];   // 16 KB
    __shared__ signed char Bs[2 * 256 * 64];   // 32 KB
    const int t    = threadIdx.x;
    const int wave = t >> 6;
    const int lane = t & 63;
    const int m0 = blockIdx.y * 128;
    const int n0 = blockIdx.x * 256;
    const int wm = (wave >> 1) * 64;    // wave row offset (M)
    const int wn = (wave & 1) * 128;    // wave col offset (N)

    v4i acc[4][8] = {};

    // staging: 256 threads x 16B = 4KB per call (64 rows of 64B)
    const int rowS = t >> 2;                           // 0..63
    const int colS = ((t & 3) ^ ((t >> 3) & 3)) * 16;  // swizzled source chunk
    const signed char* gA = A + (size_t)(m0 + rowS) * IN_F + colS;
    const signed char* gB = B + (size_t)(n0 + rowS) * IN_F + colS;
    signed char* lA = As + t * 16;                     // linear dest (HW constraint)
    signed char* lB = Bs + t * 16;

    const int r16 = lane & 15;
    const int q   = lane >> 4;
    const int cOff = ((q ^ ((r16 >> 1) & 3)) * 16);    // swizzled read chunk

    // prologue: stage tile 0 into buffer 0
    gload_lds16(gA, lA);
    gload_lds16(gA + (size_t)64 * IN_F, lA + 4096);
    gload_lds16(gB, lB);
    gload_lds16(gB + (size_t)64 * IN_F, lB + 4096);
    gload_lds16(gB + (size_t)128 * IN_F, lB + 8192);
    gload_lds16(gB + (size_t)192 * IN_F, lB + 12288);

    int buf = 0;
    for (int k0 = 0; k0 < IN_F; k0 += 64) {
        __syncthreads();   // drains current buffer's loads; protects prev reads

        const int kn = k0 + 64;
        if (kn < IN_F) {
            const int nb = (buf ^ 1) * 4096 * 2;       // byte offset scale below
            signed char* nA = lA + (buf ^ 1) * 8192;
            signed char* nB = lB + (buf ^ 1) * 16384;
            gload_lds16(gA + kn, nA);
            gload_lds16(gA + (size_t)64 * IN_F + kn, nA + 4096);
            gload_lds16(gB + kn, nB);
            gload_lds16(gB + (size_t)64 * IN_F + kn, nB + 4096);
            gload_lds16(gB + (size_t)128 * IN_F + kn, nB + 8192);
            gload_lds16(gB + (size_t)192 * IN_F + kn, nB + 12288);
            (void)nb;
        }

        const signed char* pA = As + buf * 8192;
        const signed char* pB = Bs + buf * 16384;
        v4i a[4], b[8];
#pragma unroll
        for (int i = 0; i < 4; ++i)
            a[i] = *(const v4i*)(pA + (wm + i * 16 + r16) * 64 + cOff);
#pragma unroll
        for (int j = 0; j < 8; ++j)
            b[j] = *(const v4i*)(pB + (wn + j * 16 + r16) * 64 + cOff);
#pragma unroll
        for (int i = 0; i < 4; ++i)
#pragma unroll
            for (int j = 0; j < 8; ++j)
                acc[i][j] = __builtin_amdgcn_mfma_i32_16x16x64_i8(a[i], b[j], acc[i][j], 0, 0, 0);

        buf ^= 1;
    }

    const float rws = 1.0f / wscale[0];
#pragma unroll
    for (int i = 0; i < 4; ++i) {
#pragma unroll
        for (int r = 0; r < 4; ++r) {
            const int row = m0 + wm + i * 16 + q * 4 + r;
            const float rs = recip_s[row] * rws;
#pragma unroll
            for (int j = 0; j < 8; ++j) {
                const int col = n0 + wn + j * 16 + r16;
                out[(size_t)row * OUT_F + col] = (float)acc[i][j][r] * rs + bias[col];
            }
        }
    }
}

extern "C" void kernel_launch(void* const* d_in, const int* in_sizes, int n_in,
                              void* d_out, int out_size, void* d_ws, size_t ws_size,
                              hipStream_t stream) {
    const float* x      = (const float*)d_in[0];
    const int*   w      = (const int*)d_in[1];
    const float* wscale = (const float*)d_in[2];
    const float* bias   = (const float*)d_in[3];
    float* out = (float*)d_out;

    signed char* xq = (signed char*)d_ws;                          // 32 MB
    signed char* w8 = xq + (size_t)TOKENS * IN_F;                  // 64 MB
    float* recip_s  = (float*)(w8 + (size_t)OUT_F * IN_F);         // 16 KB

    quant_kernel<<<TOKENS, 256, 0, stream>>>(x, xq, recip_s);
    pack_w<<<(int)(((size_t)OUT_F * IN_F) / 4 / 256), 256, 0, stream>>>(w, (unsigned int*)w8);
    dim3 grid(OUT_F / 256, TOKENS / 128);
    gemm_kernel<<<grid, 256, 0, stream>>>(xq, w8, recip_s, wscale, bias, out);
}

// Round 4
// 740.412 us; speedup vs baseline: 1.0335x; 1.0335x over previous
//
#include <hip/hip_runtime.h>

#define TOKENS 4096
#define IN_F   8192
#define OUT_F  8192

typedef int v4i __attribute__((ext_vector_type(4)));

__device__ __forceinline__ void gload_lds16(const void* g, void* l) {
    __builtin_amdgcn_global_load_lds(
        (const __attribute__((address_space(1))) void*)g,
        (__attribute__((address_space(3))) void*)l, 16, 0, 0);
}

// ---------------- Kernel 1: per-row absmax + int8 quantize ----------------
__global__ __launch_bounds__(256) void quant_kernel(const float* __restrict__ x,
                                                    signed char* __restrict__ xq,
                                                    float* __restrict__ recip_s) {
    const int row = blockIdx.x;
    const int t   = threadIdx.x;
    const float4* xr = (const float4*)(x + (size_t)row * IN_F);
    float4 v[8];
    float m = 0.f;
#pragma unroll
    for (int i = 0; i < 8; ++i) {
        v[i] = xr[t + 256 * i];
        m = fmaxf(m, fmaxf(fmaxf(fabsf(v[i].x), fabsf(v[i].y)),
                           fmaxf(fabsf(v[i].z), fabsf(v[i].w))));
    }
#pragma unroll
    for (int off = 32; off > 0; off >>= 1)
        m = fmaxf(m, __shfl_xor(m, off));
    __shared__ float wmax[4];
    if ((t & 63) == 0) wmax[t >> 6] = m;
    __syncthreads();
    m = fmaxf(fmaxf(wmax[0], wmax[1]), fmaxf(wmax[2], wmax[3]));
    m = fmaxf(m, 1e-5f);
    const float s = 127.0f / m;          // matches ref: s = 127/clip(max,1e-5)
    if (t == 0) recip_s[row] = m / 127.0f;
    unsigned int* out = (unsigned int*)(xq + (size_t)row * IN_F);
#pragma unroll
    for (int i = 0; i < 8; ++i) {
        int a = (int)fminf(fmaxf(rintf(v[i].x * s), -128.f), 127.f);
        int b = (int)fminf(fmaxf(rintf(v[i].y * s), -128.f), 127.f);
        int c = (int)fminf(fmaxf(rintf(v[i].z * s), -128.f), 127.f);
        int d = (int)fminf(fmaxf(rintf(v[i].w * s), -128.f), 127.f);
        out[t + 256 * i] = (a & 255) | ((b & 255) << 8) | ((c & 255) << 16) | ((d & 255) << 24);
    }
}

// ---------------- Kernel 2: weight int32 {0,1} -> int8 ----------------
__global__ __launch_bounds__(256) void pack_w(const int* __restrict__ w,
                                              unsigned int* __restrict__ w8) {
    const size_t idx = (size_t)blockIdx.x * 256 + threadIdx.x;
    int4 a = ((const int4*)w)[idx];
    w8[idx] = (a.x & 255) | ((a.y & 255) << 8) | ((a.z & 255) << 16) | ((a.w & 255) << 24);
}

// ---------------- Kernel 3: i8 GEMM, 128x256 tile, BK=64 ------------------
// Double-buffered LDS, AITER-style pipelined K-loop using RAW s_barrier +
// hand-written s_waitcnt (inline asm) instead of __syncthreads(), so the
// prefetch global_load_lds for tile k+1 stays in flight across the barrier:
//   issue loads(k+1 -> buf^1)
//   s_waitcnt vmcnt(6) lgkmcnt(0); s_barrier   // waits only tile-k loads
//   compute tile k from buf
//   s_waitcnt lgkmcnt(0); s_barrier            // reads drained; no vmem wait
// LDS chunk swizzle: 16B chunk c of row r stored at position c ^ ((r>>1)&3).
__global__ __launch_bounds__(256, 2) void gemm_kernel(const signed char* __restrict__ A,
                                                      const signed char* __restrict__ B,
                                                      const float* __restrict__ recip_s,
                                                      const float* __restrict__ wscale,
                                                      const float* __restrict__ bias,
                                                      float* __restrict__ out) {
    __shared__ signed char As[2 * 128 * 64];   // 16 KB
    __shared__ signed char Bs[2 * 256 * 64];   // 32 KB
    const int t    = threadIdx.x;
    const int wave = t >> 6;
    const int lane = t & 63;
    const int m0 = blockIdx.y * 128;
    const int n0 = blockIdx.x * 256;
    const int wm = (wave >> 1) * 64;    // wave row offset (M)
    const int wn = (wave & 1) * 128;    // wave col offset (N)

    v4i acc[4][8] = {};

    // staging: 256 threads x 16B = 4KB per call (64 rows of 64B)
    const int rowS = t >> 2;                           // 0..63
    const int colS = ((t & 3) ^ ((t >> 3) & 3)) * 16;  // swizzled source chunk
    const signed char* gA = A + (size_t)(m0 + rowS) * IN_F + colS;
    const signed char* gB = B + (size_t)(n0 + rowS) * IN_F + colS;
    signed char* lA = As + t * 16;                     // linear dest (HW constraint)
    signed char* lB = Bs + t * 16;

    const int r16 = lane & 15;
    const int q   = lane >> 4;
    const int cOff = ((q ^ ((r16 >> 1) & 3)) * 16);    // swizzled read chunk

    // prologue: stage tile 0 into buffer 0
    gload_lds16(gA, lA);
    gload_lds16(gA + (size_t)64 * IN_F, lA + 4096);
    gload_lds16(gB, lB);
    gload_lds16(gB + (size_t)64 * IN_F, lB + 4096);
    gload_lds16(gB + (size_t)128 * IN_F, lB + 8192);
    gload_lds16(gB + (size_t)192 * IN_F, lB + 12288);

    int buf = 0;
    for (int k0 = 0; k0 < IN_F; k0 += 64) {
        const int kn = k0 + 64;
        if (kn < IN_F) {
            // prefetch tile k+1 into the other buffer; stays in flight
            signed char* nA = lA + (buf ^ 1) * 8192;
            signed char* nB = lB + (buf ^ 1) * 16384;
            gload_lds16(gA + kn, nA);
            gload_lds16(gA + (size_t)64 * IN_F + kn, nA + 4096);
            gload_lds16(gB + kn, nB);
            gload_lds16(gB + (size_t)64 * IN_F + kn, nB + 4096);
            gload_lds16(gB + (size_t)128 * IN_F + kn, nB + 8192);
            gload_lds16(gB + (size_t)192 * IN_F + kn, nB + 12288);
            asm volatile("s_waitcnt vmcnt(6) lgkmcnt(0)" ::: "memory");
        } else {
            asm volatile("s_waitcnt vmcnt(0) lgkmcnt(0)" ::: "memory");
        }
        asm volatile("s_barrier" ::: "memory");   // all waves' tile-k loads done

        const signed char* pA = As + buf * 8192;
        const signed char* pB = Bs + buf * 16384;
        v4i a[4], b[8];
#pragma unroll
        for (int i = 0; i < 4; ++i)
            a[i] = *(const v4i*)(pA + (wm + i * 16 + r16) * 64 + cOff);
#pragma unroll
        for (int j = 0; j < 8; ++j)
            b[j] = *(const v4i*)(pB + (wn + j * 16 + r16) * 64 + cOff);
#pragma unroll
        for (int i = 0; i < 4; ++i)
#pragma unroll
            for (int j = 0; j < 8; ++j)
                acc[i][j] = __builtin_amdgcn_mfma_i32_16x16x64_i8(a[i], b[j], acc[i][j], 0, 0, 0);

        asm volatile("s_waitcnt lgkmcnt(0)" ::: "memory");  // own reads landed
        asm volatile("s_barrier" ::: "memory");             // safe to overwrite buf
        buf ^= 1;
    }

    const float rws = 1.0f / wscale[0];
#pragma unroll
    for (int i = 0; i < 4; ++i) {
#pragma unroll
        for (int r = 0; r < 4; ++r) {
            const int row = m0 + wm + i * 16 + q * 4 + r;
            const float rs = recip_s[row] * rws;
#pragma unroll
            for (int j = 0; j < 8; ++j) {
                const int col = n0 + wn + j * 16 + r16;
                out[(size_t)row * OUT_F + col] = (float)acc[i][j][r] * rs + bias[col];
            }
        }
    }
}

extern "C" void kernel_launch(void* const* d_in, const int* in_sizes, int n_in,
                              void* d_out, int out_size, void* d_ws, size_t ws_size,
                              hipStream_t stream) {
    const float* x      = (const float*)d_in[0];
    const int*   w      = (const int*)d_in[1];
    const float* wscale = (const float*)d_in[2];
    const float* bias   = (const float*)d_in[3];
    float* out = (float*)d_out;

    signed char* xq = (signed char*)d_ws;                          // 32 MB
    signed char* w8 = xq + (size_t)TOKENS * IN_F;                  // 64 MB
    float* recip_s  = (float*)(w8 + (size_t)OUT_F * IN_F);         // 16 KB

    quant_kernel<<<TOKENS, 256, 0, stream>>>(x, xq, recip_s);
    pack_w<<<(int)(((size_t)OUT_F * IN_F) / 4 / 256), 256, 0, stream>>>(w, (unsigned int*)w8);
    dim3 grid(OUT_F / 256, TOKENS / 128);
    gemm_kernel<<<grid, 256, 0, stream>>>(xq, w8, recip_s, wscale, bias, out);
}